// Round 1
// baseline (445.654 us; speedup 1.0000x reference)
//
#include <hip/hip_runtime.h>
#include <math.h>

#define EPS 1e-6f

__device__ __forceinline__ float elu1(float x) {
    // elu(x) + 1  ==  x+1 (x>0)  |  exp(x) (x<=0)
    return x > 0.0f ? x + 1.0f : __expf(x);
}

// One block per (b,n). D = M = 256. 256 threads = 4 waves of 64 lanes.
// Wave w handles Si rows d = d0 + w; lane c handles columns 4c..4c+3 (float4).
__global__ __launch_bounds__(256) void rla_kernel(
    const float* __restrict__ query,
    const float* __restrict__ key,
    const float* __restrict__ value,
    const float* __restrict__ Si,
    const float* __restrict__ Zi,
    float* __restrict__ V_out,
    float* __restrict__ Si_out,
    float* __restrict__ Zi_out)
{
    const int bn = blockIdx.x;      // 0 .. B*N-1
    const int t  = threadIdx.x;     // 0 .. 255

    __shared__ float sQ[256];
    __shared__ float sK[256];
    __shared__ float red[4 * 256];
    __shared__ float sden[4];
    __shared__ float sZ;

    const size_t base = (size_t)bn * 256;

    // ---- Phase 1: feature maps, Zi_new, denominator reduction ----
    float q  = elu1(query[base + t]);
    float k  = elu1(key[base + t]);
    float zn = Zi[base + t] + k;
    Zi_out[base + t] = zn;
    sQ[t] = q;
    sK[t] = k;

    float part = q * zn;
    #pragma unroll
    for (int off = 32; off > 0; off >>= 1)
        part += __shfl_down(part, off, 64);
    if ((t & 63) == 0) sden[t >> 6] = part;
    __syncthreads();                 // sQ/sK/sden visible
    if (t == 0) {
        float den = sden[0] + sden[1] + sden[2] + sden[3];
        sZ = 1.0f / (den + EPS);
    }

    // ---- Phase 2: Si sweep (the bandwidth-dominant part) ----
    const int c = t & 63;            // column group
    const int w = t >> 6;            // wave id = row offset within group of 4

    const float4 v = ((const float4*)(value + base))[c];

    const float* SiB = Si    + (size_t)bn * 256 * 256;
    float*       SoB = Si_out + (size_t)bn * 256 * 256;

    float4 acc = make_float4(0.f, 0.f, 0.f, 0.f);

    #pragma unroll 4
    for (int d0 = 0; d0 < 256; d0 += 4) {
        const int d = d0 + w;
        const float kk = sK[d];      // wave-uniform broadcast, no conflict
        const float qq = sQ[d];
        const float4 si = ((const float4*)(SiB + (size_t)d * 256))[c];
        float4 sn;
        sn.x = si.x + kk * v.x;
        sn.y = si.y + kk * v.y;
        sn.z = si.z + kk * v.z;
        sn.w = si.w + kk * v.w;
        ((float4*)(SoB + (size_t)d * 256))[c] = sn;
        acc.x += qq * sn.x;
        acc.y += qq * sn.y;
        acc.z += qq * sn.z;
        acc.w += qq * sn.w;
    }

    // ---- Combine the 4 waves' partial V, scale by Z ----
    ((float4*)(red + w * 256))[c] = acc;
    __syncthreads();                 // red + sZ visible
    const float vsum = red[0 * 256 + t] + red[1 * 256 + t]
                     + red[2 * 256 + t] + red[3 * 256 + t];
    V_out[base + t] = vsum * sZ;
}

extern "C" void kernel_launch(void* const* d_in, const int* in_sizes, int n_in,
                              void* d_out, int out_size, void* d_ws, size_t ws_size,
                              hipStream_t stream) {
    const float* query = (const float*)d_in[0];
    const float* key_  = (const float*)d_in[1];
    const float* value = (const float*)d_in[2];
    const float* Si    = (const float*)d_in[3];
    const float* Zi    = (const float*)d_in[4];

    const int BN = in_sizes[0] / 256;          // B*N = 1024
    float* V_out  = (float*)d_out;                             // [BN, 256]
    float* Si_out = V_out + (size_t)BN * 256;                  // [BN, 256, 256]
    float* Zi_out = Si_out + (size_t)BN * 256 * 256;           // [BN, 256]

    rla_kernel<<<BN, 256, 0, stream>>>(query, key_, value, Si, Zi,
                                       V_out, Si_out, Zi_out);
}

// Round 2
// 438.256 us; speedup vs baseline: 1.0169x; 1.0169x over previous
//
#include <hip/hip_runtime.h>
#include <math.h>

#define EPS 1e-6f

typedef float f4 __attribute__((ext_vector_type(4)));

__device__ __forceinline__ float elu1(float x) {
    // elu(x) + 1  ==  x+1 (x>0)  |  exp(x) (x<=0)
    return x > 0.0f ? x + 1.0f : __expf(x);
}

// One block per (b,n). D = M = 256. 256 threads = 4 waves of 64 lanes.
// Wave w handles Si rows d ≡ w (mod 4); each iteration a thread processes TWO
// rows (d0+w, d0+w+4) so unroll-4 keeps 8 independent 16B loads in flight.
// Si/Si_new are streamed with nontemporal loads/stores (no reuse; keep L2
// for the small Q/K/V/Zi tensors).
__global__ __launch_bounds__(256) void rla_kernel(
    const float* __restrict__ query,
    const float* __restrict__ key,
    const float* __restrict__ value,
    const float* __restrict__ Si,
    const float* __restrict__ Zi,
    float* __restrict__ V_out,
    float* __restrict__ Si_out,
    float* __restrict__ Zi_out)
{
    const int bn = blockIdx.x;      // 0 .. B*N-1
    const int t  = threadIdx.x;     // 0 .. 255

    __shared__ float sQ[256];
    __shared__ float sK[256];
    __shared__ float red[4 * 256];
    __shared__ float sden[4];
    __shared__ float sZ;

    const size_t base = (size_t)bn * 256;

    // ---- Phase 1: feature maps, Zi_new, denominator reduction ----
    float q  = elu1(query[base + t]);
    float k  = elu1(key[base + t]);
    float zn = Zi[base + t] + k;
    Zi_out[base + t] = zn;
    sQ[t] = q;
    sK[t] = k;

    float part = q * zn;
    #pragma unroll
    for (int off = 32; off > 0; off >>= 1)
        part += __shfl_down(part, off, 64);
    if ((t & 63) == 0) sden[t >> 6] = part;
    __syncthreads();                 // sQ/sK/sden visible
    if (t == 0) {
        float den = sden[0] + sden[1] + sden[2] + sden[3];
        sZ = 1.0f / (den + EPS);
    }

    // ---- Phase 2: Si sweep (the bandwidth-dominant part) ----
    const int c = t & 63;            // column group (lane)
    const int w = t >> 6;            // wave id = row offset within group of 4

    const f4 v = ((const f4*)(value + base))[c];

    const f4* SiB = (const f4*)(Si     + (size_t)bn * 256 * 256) + c;
    f4*       SoB = (f4*)      (Si_out + (size_t)bn * 256 * 256) + c;
    // row stride in f4 units = 64

    f4 acc = (f4)(0.0f);

    #pragma unroll 4
    for (int d0 = 0; d0 < 256; d0 += 8) {
        const int dA = d0 + w;
        const int dB = dA + 4;
        const float kA = sK[dA];     // wave-uniform broadcast
        const float qA = sQ[dA];
        const float kB = sK[dB];
        const float qB = sQ[dB];
        f4 sa = __builtin_nontemporal_load(SiB + (size_t)dA * 64);
        f4 sb = __builtin_nontemporal_load(SiB + (size_t)dB * 64);
        f4 na = sa + kA * v;
        f4 nb = sb + kB * v;
        __builtin_nontemporal_store(na, SoB + (size_t)dA * 64);
        __builtin_nontemporal_store(nb, SoB + (size_t)dB * 64);
        acc += qA * na;
        acc += qB * nb;
    }

    // ---- Combine the 4 waves' partial V, scale by Z ----
    ((f4*)(red + w * 256))[c] = acc;
    __syncthreads();                 // red + sZ visible
    const float vsum = red[0 * 256 + t] + red[1 * 256 + t]
                     + red[2 * 256 + t] + red[3 * 256 + t];
    V_out[base + t] = vsum * sZ;
}

extern "C" void kernel_launch(void* const* d_in, const int* in_sizes, int n_in,
                              void* d_out, int out_size, void* d_ws, size_t ws_size,
                              hipStream_t stream) {
    const float* query = (const float*)d_in[0];
    const float* key_  = (const float*)d_in[1];
    const float* value = (const float*)d_in[2];
    const float* Si    = (const float*)d_in[3];
    const float* Zi    = (const float*)d_in[4];

    const int BN = in_sizes[0] / 256;          // B*N = 1024
    float* V_out  = (float*)d_out;                             // [BN, 256]
    float* Si_out = V_out + (size_t)BN * 256;                  // [BN, 256, 256]
    float* Zi_out = Si_out + (size_t)BN * 256 * 256;           // [BN, 256]

    rla_kernel<<<BN, 256, 0, stream>>>(query, key_, value, Si, Zi,
                                       V_out, Si_out, Zi_out);
}